// Round 1
// baseline (848.284 us; speedup 1.0000x reference)
//
#include <hip/hip_runtime.h>

#define GX 200
#define GY 200
#define GZ 16
#define NVOX (GX*GY*GZ)
#define NFEAT 8

__global__ __launch_bounds__(512) void splat_kernel(
    const float* __restrict__ means, const float* __restrict__ opac,
    const float* __restrict__ cov, const float* __restrict__ feat,
    float* __restrict__ dens_out, float* __restrict__ feat_out)
{
    const int g = blockIdx.x;
    const int t = threadIdx.x;

    const float lox = -40.f, loy = -40.f, loz = -1.f;
    const float hix =  40.f, hiy =  40.f, hiz =  5.4f;

    // broadcast loads (same address across all threads -> L1 broadcast)
    const float mx = means[g*3+0], my = means[g*3+1], mz = means[g*3+2];
    const float c00 = cov[g*9+0], c01 = cov[g*9+1], c02 = cov[g*9+2];
    const float c10 = cov[g*9+3], c11 = cov[g*9+4], c12 = cov[g*9+5];
    const float c20 = cov[g*9+6], c21 = cov[g*9+7], c22 = cov[g*9+8];

    const float sx = sqrtf(c00), sy = sqrtf(c11), sz = sqrtf(c22);
    const float blx = mx - 3.0f*sx, bly = my - 3.0f*sy, blz = mz - 3.0f*sz;
    const float bhx = mx + 3.0f*sx, bhy = my + 3.0f*sy, bhz = mz + 3.0f*sz;

    const bool valid = (bhx > lox) & (bhy > loy) & (bhz > loz)
                     & (blx < hix) & (bly < hiy) & (blz < hiz);
    if (!valid) return;

    // clip box, convert to voxel index range (match reference ops exactly)
    float blxc = fminf(fmaxf(blx, lox), hix);
    float blyc = fminf(fmaxf(bly, loy), hiy);
    float blzc = fminf(fmaxf(blz, loz), hiz);
    float bhxc = fminf(fmaxf(bhx, lox), hix);
    float bhyc = fminf(fmaxf(bhy, loy), hiy);
    float bhzc = fminf(fmaxf(bhz, loz), hiz);

    int ilox = (int)((blxc - lox) / 0.4f);
    int iloy = (int)((blyc - loy) / 0.4f);
    int iloz = (int)((blzc - loz) / 0.4f);
    int ihix = (int)((bhxc - lox) / 0.4f);
    int ihiy = (int)((bhyc - loy) / 0.4f);
    int ihiz = (int)((bhzc - loz) / 0.4f);
    ilox = min(ilox, GX-1); iloy = min(iloy, GY-1); iloz = min(iloz, GZ-1);
    ihix = min(ihix, GX-1); ihiy = min(ihiy, GY-1); ihiz = min(ihiz, GZ-1);

    // candidate voxel for this thread; dx wave-uniform so whole waves exit
    const int ix = ilox + (t >> 6);
    if (ix > ihix) return;
    const int iy = iloy + ((t >> 3) & 7);
    if (iy > ihiy) return;
    const int iz = iloz + (t & 7);
    if (iz > ihiz) return;

    // inverse covariance (adjugate / det)
    const float m00 = c11*c22 - c12*c21;
    const float m01 = c10*c22 - c12*c20;
    const float m02 = c10*c21 - c11*c20;
    const float det = c00*m00 - c01*m01 + c02*m02;
    const float idet = 1.0f / det;
    const float A00 = m00 * idet;
    const float A11 = (c00*c22 - c02*c20) * idet;
    const float A22 = (c00*c11 - c01*c10) * idet;
    const float A01 = (c02*c21 - c01*c22) * idet;
    const float A02 = (c01*c12 - c02*c11) * idet;
    const float A12 = (c02*c10 - c00*c12) * idet;

    const float X = ((float)ix + 0.5f) * 0.4f + lox - mx;
    const float Y = ((float)iy + 0.5f) * 0.4f + loy - my;
    const float Z = ((float)iz + 0.5f) * 0.4f + loz - mz;

    const float maha = A00*X*X + A11*Y*Y + A22*Z*Z
                     + 2.0f*A01*X*Y + 2.0f*A02*X*Z + 2.0f*A12*Y*Z;
    const float w = opac[g] * expf(-0.5f * maha);

    const int flat = (ix*GY + iy)*GZ + iz;
    atomicAdd(dens_out + flat, w);
    float* fo = feat_out + (size_t)flat * NFEAT;
    const float* fg = feat + (size_t)g * NFEAT;
    #pragma unroll
    for (int f = 0; f < NFEAT; ++f)
        atomicAdd(fo + f, w * fg[f]);
}

__global__ __launch_bounds__(256) void norm_kernel(
    const float* __restrict__ dens, float* __restrict__ feats)
{
    const int v = blockIdx.x * blockDim.x + threadIdx.x;
    if (v >= NVOX) return;
    const float d = fmaxf(dens[v], 1e-6f);
    float4* fp = (float4*)(feats + (size_t)v * NFEAT);
    float4 a = fp[0], b = fp[1];
    a.x /= d; a.y /= d; a.z /= d; a.w /= d;
    b.x /= d; b.y /= d; b.z /= d; b.w /= d;
    fp[0] = a; fp[1] = b;
}

extern "C" void kernel_launch(void* const* d_in, const int* in_sizes, int n_in,
                              void* d_out, int out_size, void* d_ws, size_t ws_size,
                              hipStream_t stream) {
    const float* means = (const float*)d_in[0];
    const float* opac  = (const float*)d_in[1];
    const float* cov   = (const float*)d_in[2];
    const float* feat  = (const float*)d_in[3];
    const int G = in_sizes[0] / 3;

    float* dens_out = (float*)d_out;
    float* feat_out = dens_out + NVOX;

    hipMemsetAsync(d_out, 0, (size_t)out_size * sizeof(float), stream);
    splat_kernel<<<G, 512, 0, stream>>>(means, opac, cov, feat, dens_out, feat_out);
    norm_kernel<<<(NVOX + 255) / 256, 256, 0, stream>>>(dens_out, feat_out);
}

// Round 2
// 140.748 us; speedup vs baseline: 6.0270x; 6.0270x over previous
//
#include <hip/hip_runtime.h>

#define GX 200
#define GY 200
#define GZ 16
#define NVOX (GX*GY*GZ)
#define NFEAT 8

#define TX 4
#define TY 4
// tile z = full GZ (16). tiles: 50 x 50
#define NTX (GX/TX)   // 50
#define NTY (GY/TY)   // 50
#define NTILES (NTX*NTY)  // 2500
#define MAXPAIRS (32768*9)

// ws layout (ints)
#define WS_COUNTS 0
#define WS_OFFS   (NTILES)
#define WS_CURSOR (2*NTILES)
#define WS_PAIRS  (3*NTILES)

__device__ inline bool gauss_ranges(const float* __restrict__ means,
                                    const float* __restrict__ cov, int g,
                                    int& ilox,int& iloy,int& iloz,
                                    int& ihix,int& ihiy,int& ihiz)
{
    const float lox = -40.f, loy = -40.f, loz = -1.f;
    const float hix =  40.f, hiy =  40.f, hiz =  5.4f;
    const float mx = means[g*3+0], my = means[g*3+1], mz = means[g*3+2];
    const float c00 = cov[g*9+0], c11 = cov[g*9+4], c22 = cov[g*9+8];
    const float sx = sqrtf(c00), sy = sqrtf(c11), sz = sqrtf(c22);
    const float blx = mx - 3.0f*sx, bly = my - 3.0f*sy, blz = mz - 3.0f*sz;
    const float bhx = mx + 3.0f*sx, bhy = my + 3.0f*sy, bhz = mz + 3.0f*sz;
    const bool valid = (bhx > lox) & (bhy > loy) & (bhz > loz)
                     & (blx < hix) & (bly < hiy) & (blz < hiz);
    if (!valid) return false;
    float blxc = fminf(fmaxf(blx, lox), hix);
    float blyc = fminf(fmaxf(bly, loy), hiy);
    float blzc = fminf(fmaxf(blz, loz), hiz);
    float bhxc = fminf(fmaxf(bhx, lox), hix);
    float bhyc = fminf(fmaxf(bhy, loy), hiy);
    float bhzc = fminf(fmaxf(bhz, loz), hiz);
    ilox = (int)((blxc - lox) / 0.4f);
    iloy = (int)((blyc - loy) / 0.4f);
    iloz = (int)((blzc - loz) / 0.4f);
    ihix = (int)((bhxc - lox) / 0.4f);
    ihiy = (int)((bhyc - loy) / 0.4f);
    ihiz = (int)((bhzc - loz) / 0.4f);
    ilox = min(ilox, GX-1); iloy = min(iloy, GY-1); iloz = min(iloz, GZ-1);
    ihix = min(ihix, GX-1); ihiy = min(ihiy, GY-1); ihiz = min(ihiz, GZ-1);
    return true;
}

__global__ __launch_bounds__(256) void count_kernel(
    const float* __restrict__ means, const float* __restrict__ cov,
    int* __restrict__ ws, int G)
{
    int g = blockIdx.x*256 + threadIdx.x;
    if (g >= G) return;
    int ilox,iloy,iloz,ihix,ihiy,ihiz;
    if (!gauss_ranges(means, cov, g, ilox,iloy,iloz,ihix,ihiy,ihiz)) return;
    int txlo = ilox >> 2, txhi = ihix >> 2;
    int tylo = iloy >> 2, tyhi = ihiy >> 2;
    for (int tx = txlo; tx <= txhi; ++tx)
        for (int ty = tylo; ty <= tyhi; ++ty)
            atomicAdd(&ws[WS_COUNTS + tx*NTY + ty], 1);
}

__global__ __launch_bounds__(1024) void scan_kernel(int* __restrict__ ws)
{
    __shared__ int buf[2][2560];
    int t = threadIdx.x;
    for (int i = t; i < 2560; i += 1024)
        buf[0][i] = (i < NTILES) ? ws[WS_COUNTS + i] : 0;
    __syncthreads();
    int src = 0;
    for (int stride = 1; stride < 2560; stride <<= 1) {
        for (int i = t; i < 2560; i += 1024) {
            int v = buf[src][i];
            if (i >= stride) v += buf[src][i - stride];
            buf[1-src][i] = v;
        }
        __syncthreads();
        src = 1 - src;
    }
    for (int i = t; i < NTILES; i += 1024) {
        int excl = (i > 0) ? buf[src][i-1] : 0;
        ws[WS_OFFS + i] = excl;
        ws[WS_CURSOR + i] = excl;
    }
}

__global__ __launch_bounds__(256) void fill_kernel(
    const float* __restrict__ means, const float* __restrict__ cov,
    int* __restrict__ ws, int G)
{
    int g = blockIdx.x*256 + threadIdx.x;
    if (g >= G) return;
    int ilox,iloy,iloz,ihix,ihiy,ihiz;
    if (!gauss_ranges(means, cov, g, ilox,iloy,iloz,ihix,ihiy,ihiz)) return;
    int txlo = ilox >> 2, txhi = ihix >> 2;
    int tylo = iloy >> 2, tyhi = ihiy >> 2;
    for (int tx = txlo; tx <= txhi; ++tx)
        for (int ty = tylo; ty <= tyhi; ++ty) {
            int slot = atomicAdd(&ws[WS_CURSOR + tx*NTY + ty], 1);
            ws[WS_PAIRS + slot] = g;
        }
}

// per-gaussian LDS record: 20 floats
// [0..5]=A00,A01,A02,A11,A12,A22  [6]=opac  [7..9]=mean  [10]=loPack [11]=hiPack  [12..19]=feats
#define REC 20
#define CHUNK 64

__global__ __launch_bounds__(256) void gather_kernel(
    const float* __restrict__ means, const float* __restrict__ opac,
    const float* __restrict__ cov, const float* __restrict__ feat,
    const int* __restrict__ ws,
    float* __restrict__ dens_out, float* __restrict__ feat_out)
{
    __shared__ float lds[CHUNK * REC];
    const int tile = blockIdx.x;
    const int tx = tile / NTY, ty = tile % NTY;
    const int t = threadIdx.x;
    const int lz = t & 15, ly = (t >> 4) & 3, lx = t >> 6;
    const int ix = tx*TX + lx, iy = ty*TY + ly, iz = lz;

    const float cx = ((float)ix + 0.5f) * 0.4f + (-40.f);
    const float cy = ((float)iy + 0.5f) * 0.4f + (-40.f);
    const float cz = ((float)iz + 0.5f) * 0.4f + (-1.f);

    const int start = ws[WS_OFFS + tile];
    const int n = ws[WS_COUNTS + tile];

    float den = 0.f;
    float f0=0,f1=0,f2=0,f3=0,f4=0,f5=0,f6=0,f7=0;

    for (int c = 0; c < n; c += CHUNK) {
        const int m = min(CHUNK, n - c);
        if (t < m) {
            const int g = ws[WS_PAIRS + start + c + t];
            const float c00 = cov[g*9+0], c01 = cov[g*9+1], c02 = cov[g*9+2];
            const float c10 = cov[g*9+3], c11 = cov[g*9+4], c12 = cov[g*9+5];
            const float c20 = cov[g*9+6], c21 = cov[g*9+7], c22 = cov[g*9+8];
            const float m00 = c11*c22 - c12*c21;
            const float m01 = c10*c22 - c12*c20;
            const float m02 = c10*c21 - c11*c20;
            const float det = c00*m00 - c01*m01 + c02*m02;
            const float idet = 1.0f / det;
            float* r = &lds[t * REC];
            r[0] = m00 * idet;                       // A00
            r[1] = (c02*c21 - c01*c22) * idet;       // A01
            r[2] = (c01*c12 - c02*c11) * idet;       // A02
            r[3] = (c00*c22 - c02*c20) * idet;       // A11
            r[4] = (c02*c10 - c00*c12) * idet;       // A12
            r[5] = (c00*c11 - c01*c10) * idet;       // A22
            r[6] = opac[g];
            r[7] = means[g*3+0]; r[8] = means[g*3+1]; r[9] = means[g*3+2];
            int ilox,iloy,iloz,ihix,ihiy,ihiz;
            gauss_ranges(means, cov, g, ilox,iloy,iloz,ihix,ihiy,ihiz);
            r[10] = __int_as_float(ilox | (iloy<<8) | (iloz<<16));
            r[11] = __int_as_float(ihix | (ihiy<<8) | (ihiz<<16));
            #pragma unroll
            for (int k = 0; k < NFEAT; ++k) r[12+k] = feat[g*NFEAT + k];
        }
        __syncthreads();
        for (int j = 0; j < m; ++j) {
            const float* r = &lds[j * REC];
            const int lo = __float_as_int(r[10]);
            const int hi = __float_as_int(r[11]);
            const int ilox = lo & 0xff, iloy = (lo>>8)&0xff, iloz = (lo>>16)&0xff;
            const int ihix = hi & 0xff, ihiy = (hi>>8)&0xff, ihiz = (hi>>16)&0xff;
            if (ix >= ilox && ix <= ihix && iy >= iloy && iy <= ihiy
                && iz >= iloz && iz <= ihiz) {
                const float X = cx - r[7], Y = cy - r[8], Z = cz - r[9];
                const float maha = r[0]*X*X + r[3]*Y*Y + r[5]*Z*Z
                                 + 2.0f*(r[1]*X*Y + r[2]*X*Z + r[4]*Y*Z);
                const float w = r[6] * expf(-0.5f * maha);
                den += w;
                f0 += w*r[12]; f1 += w*r[13]; f2 += w*r[14]; f3 += w*r[15];
                f4 += w*r[16]; f5 += w*r[17]; f6 += w*r[18]; f7 += w*r[19];
            }
        }
        __syncthreads();
    }

    const int flat = (ix*GY + iy)*GZ + iz;
    dens_out[flat] = den;
    const float dc = fmaxf(den, 1e-6f);
    float4 fa, fb;
    fa.x = f0/dc; fa.y = f1/dc; fa.z = f2/dc; fa.w = f3/dc;
    fb.x = f4/dc; fb.y = f5/dc; fb.z = f6/dc; fb.w = f7/dc;
    float4* fp = (float4*)(feat_out + (size_t)flat * NFEAT);
    fp[0] = fa; fp[1] = fb;
}

extern "C" void kernel_launch(void* const* d_in, const int* in_sizes, int n_in,
                              void* d_out, int out_size, void* d_ws, size_t ws_size,
                              hipStream_t stream) {
    const float* means = (const float*)d_in[0];
    const float* opac  = (const float*)d_in[1];
    const float* cov   = (const float*)d_in[2];
    const float* feat  = (const float*)d_in[3];
    const int G = in_sizes[0] / 3;

    float* dens_out = (float*)d_out;
    float* feat_out = dens_out + NVOX;
    int* ws = (int*)d_ws;

    hipMemsetAsync(ws, 0, NTILES * sizeof(int), stream);
    count_kernel<<<(G + 255)/256, 256, 0, stream>>>(means, cov, ws, G);
    scan_kernel<<<1, 1024, 0, stream>>>(ws);
    fill_kernel<<<(G + 255)/256, 256, 0, stream>>>(means, cov, ws, G);
    gather_kernel<<<NTILES, 256, 0, stream>>>(means, opac, cov, feat, ws,
                                              dens_out, feat_out);
}

// Round 3
// 113.399 us; speedup vs baseline: 7.4805x; 1.2412x over previous
//
#include <hip/hip_runtime.h>

#define GX 200
#define GY 200
#define GZ 16
#define NVOX (GX*GY*GZ)
#define NFEAT 8

#define NTX 50
#define NTY 50
#define NTILES (NTX*NTY)   // 2500 tiles of 4x4x16 voxels
#define CAP 160            // max gaussians binned per tile (mean ~50)

// ws layout (ints): [0,NTILES) counts, [NTILES, NTILES+NTILES*CAP) buckets
#define WS_COUNTS 0
#define WS_BUCKETS (NTILES)

__device__ inline bool gauss_ranges(const float* __restrict__ means,
                                    const float* __restrict__ cov, int g,
                                    int& ilox,int& iloy,int& iloz,
                                    int& ihix,int& ihiy,int& ihiz)
{
    const float lox = -40.f, loy = -40.f, loz = -1.f;
    const float hix =  40.f, hiy =  40.f, hiz =  5.4f;
    const float mx = means[g*3+0], my = means[g*3+1], mz = means[g*3+2];
    const float c00 = cov[g*9+0], c11 = cov[g*9+4], c22 = cov[g*9+8];
    const float sx = sqrtf(c00), sy = sqrtf(c11), sz = sqrtf(c22);
    const float blx = mx - 3.0f*sx, bly = my - 3.0f*sy, blz = mz - 3.0f*sz;
    const float bhx = mx + 3.0f*sx, bhy = my + 3.0f*sy, bhz = mz + 3.0f*sz;
    const bool valid = (bhx > lox) & (bhy > loy) & (bhz > loz)
                     & (blx < hix) & (bly < hiy) & (blz < hiz);
    if (!valid) return false;
    float blxc = fminf(fmaxf(blx, lox), hix);
    float blyc = fminf(fmaxf(bly, loy), hiy);
    float blzc = fminf(fmaxf(blz, loz), hiz);
    float bhxc = fminf(fmaxf(bhx, lox), hix);
    float bhyc = fminf(fmaxf(bhy, loy), hiy);
    float bhzc = fminf(fmaxf(bhz, loz), hiz);
    ilox = (int)((blxc - lox) / 0.4f);
    iloy = (int)((blyc - loy) / 0.4f);
    iloz = (int)((blzc - loz) / 0.4f);
    ihix = (int)((bhxc - lox) / 0.4f);
    ihiy = (int)((bhyc - loy) / 0.4f);
    ihiz = (int)((bhzc - loz) / 0.4f);
    ilox = min(ilox, GX-1); iloy = min(iloy, GY-1); iloz = min(iloz, GZ-1);
    ihix = min(ihix, GX-1); ihiy = min(ihiy, GY-1); ihiz = min(ihiz, GZ-1);
    return true;
}

// one pass: bin gaussian ids directly into fixed-capacity per-tile buckets
__global__ __launch_bounds__(256) void fill_kernel(
    const float* __restrict__ means, const float* __restrict__ cov,
    int* __restrict__ ws, int G)
{
    int g = blockIdx.x*256 + threadIdx.x;
    if (g >= G) return;
    int ilox,iloy,iloz,ihix,ihiy,ihiz;
    if (!gauss_ranges(means, cov, g, ilox,iloy,iloz,ihix,ihiy,ihiz)) return;
    int txlo = ilox >> 2, txhi = ihix >> 2;
    int tylo = iloy >> 2, tyhi = ihiy >> 2;
    for (int tx = txlo; tx <= txhi; ++tx)
        for (int ty = tylo; ty <= tyhi; ++ty) {
            int tile = tx*NTY + ty;
            int pos = atomicAdd(&ws[WS_COUNTS + tile], 1);
            if (pos < CAP) ws[WS_BUCKETS + tile*CAP + pos] = g;
        }
}

// per-gaussian LDS record: 20 floats
// [0..5]=A00,A01,A02,A11,A12,A22 [6]=opac [7..9]=mean [10]=loPack [11]=hiPack [12..19]=feats
#define REC 20

__global__ __launch_bounds__(256) void gather_kernel(
    const float* __restrict__ means, const float* __restrict__ opac,
    const float* __restrict__ cov, const float* __restrict__ feat,
    const int* __restrict__ ws,
    float* __restrict__ dens_out, float* __restrict__ feat_out)
{
    __shared__ float lds[CAP * REC];   // 12.8 KB
    const int tile = blockIdx.x;
    const int tx = tile / NTY, ty = tile % NTY;
    const int t = threadIdx.x;
    // wave w (t>>6) owns z-slab [4w,4w+4): lanes cover a 4x4x4 sub-cube so
    // gaussians missing the slab empty the exec mask -> s_cbranch_execz skip
    const int lz = (t & 3) | ((t >> 6) << 2);
    const int ly = (t >> 2) & 3;
    const int lx = (t >> 4) & 3;
    const int ix = tx*4 + lx, iy = ty*4 + ly, iz = lz;

    const float cx = ((float)ix + 0.5f) * 0.4f + (-40.f);
    const float cy = ((float)iy + 0.5f) * 0.4f + (-40.f);
    const float cz = ((float)iz + 0.5f) * 0.4f + (-1.f);

    int n = ws[WS_COUNTS + tile];
    n = min(n, CAP);   // safety clamp (never expected to trigger)

    // single-chunk staging: thread t preps record t
    if (t < n) {
        const int g = ws[WS_BUCKETS + tile*CAP + t];
        const float c00 = cov[g*9+0], c01 = cov[g*9+1], c02 = cov[g*9+2];
        const float c10 = cov[g*9+3], c11 = cov[g*9+4], c12 = cov[g*9+5];
        const float c20 = cov[g*9+6], c21 = cov[g*9+7], c22 = cov[g*9+8];
        const float m00 = c11*c22 - c12*c21;
        const float m01 = c10*c22 - c12*c20;
        const float m02 = c10*c21 - c11*c20;
        const float det = c00*m00 - c01*m01 + c02*m02;
        const float idet = 1.0f / det;
        float* r = &lds[t * REC];
        r[0] = m00 * idet;
        r[1] = (c02*c21 - c01*c22) * idet;
        r[2] = (c01*c12 - c02*c11) * idet;
        r[3] = (c00*c22 - c02*c20) * idet;
        r[4] = (c02*c10 - c00*c12) * idet;
        r[5] = (c00*c11 - c01*c10) * idet;
        r[6] = opac[g];
        r[7] = means[g*3+0]; r[8] = means[g*3+1]; r[9] = means[g*3+2];
        int ilox,iloy,iloz,ihix,ihiy,ihiz;
        gauss_ranges(means, cov, g, ilox,iloy,iloz,ihix,ihiy,ihiz);
        r[10] = __int_as_float(ilox | (iloy<<8) | (iloz<<16));
        r[11] = __int_as_float(ihix | (ihiy<<8) | (ihiz<<16));
        #pragma unroll
        for (int k = 0; k < NFEAT; ++k) r[12+k] = feat[g*NFEAT + k];
    }
    __syncthreads();

    float den = 0.f;
    float f0=0,f1=0,f2=0,f3=0,f4=0,f5=0,f6=0,f7=0;

    for (int j = 0; j < n; ++j) {
        const float* r = &lds[j * REC];
        const int lo = __float_as_int(r[10]);
        const int hi = __float_as_int(r[11]);
        const int ilox = lo & 0xff, iloy = (lo>>8)&0xff, iloz = (lo>>16)&0xff;
        const int ihix = hi & 0xff, ihiy = (hi>>8)&0xff, ihiz = (hi>>16)&0xff;
        if (ix >= ilox && ix <= ihix && iy >= iloy && iy <= ihiy
            && iz >= iloz && iz <= ihiz) {
            const float X = cx - r[7], Y = cy - r[8], Z = cz - r[9];
            const float maha = r[0]*X*X + r[3]*Y*Y + r[5]*Z*Z
                             + 2.0f*(r[1]*X*Y + r[2]*X*Z + r[4]*Y*Z);
            const float w = r[6] * __expf(-0.5f * maha);
            den += w;
            f0 += w*r[12]; f1 += w*r[13]; f2 += w*r[14]; f3 += w*r[15];
            f4 += w*r[16]; f5 += w*r[17]; f6 += w*r[18]; f7 += w*r[19];
        }
    }

    const int flat = (ix*GY + iy)*GZ + iz;
    dens_out[flat] = den;
    const float dc = fmaxf(den, 1e-6f);
    float4 fa, fb;
    fa.x = f0/dc; fa.y = f1/dc; fa.z = f2/dc; fa.w = f3/dc;
    fb.x = f4/dc; fb.y = f5/dc; fb.z = f6/dc; fb.w = f7/dc;
    float4* fp = (float4*)(feat_out + (size_t)flat * NFEAT);
    fp[0] = fa; fp[1] = fb;
}

extern "C" void kernel_launch(void* const* d_in, const int* in_sizes, int n_in,
                              void* d_out, int out_size, void* d_ws, size_t ws_size,
                              hipStream_t stream) {
    const float* means = (const float*)d_in[0];
    const float* opac  = (const float*)d_in[1];
    const float* cov   = (const float*)d_in[2];
    const float* feat  = (const float*)d_in[3];
    const int G = in_sizes[0] / 3;

    float* dens_out = (float*)d_out;
    float* feat_out = dens_out + NVOX;
    int* ws = (int*)d_ws;

    hipMemsetAsync(ws, 0, NTILES * sizeof(int), stream);
    fill_kernel<<<(G + 255)/256, 256, 0, stream>>>(means, cov, ws, G);
    gather_kernel<<<NTILES, 256, 0, stream>>>(means, opac, cov, feat, ws,
                                              dens_out, feat_out);
}

// Round 4
// 113.057 us; speedup vs baseline: 7.5032x; 1.0030x over previous
//
#include <hip/hip_runtime.h>

#define GX 200
#define GY 200
#define GZ 16
#define NVOX (GX*GY*GZ)
#define NFEAT 8

#define NTX 50
#define NTY 50
#define NTILES (NTX*NTY)      // 2500 xy-tiles of 4x4 voxels
#define NSLAB 4               // z split into 4 slabs of 4 voxels
#define NBIN (NTILES*NSLAB)   // 10000 bins
#define CAP 160               // per-bin capacity (avg occupancy ~21)

// ws layout (ints): [0,NBIN) counts | [NBIN, NBIN+NBIN*CAP) buckets | records
#define WS_COUNTS 0
#define WS_BUCKETS NBIN
#define WS_RECORDS (NBIN + NBIN*CAP)   // 1,610,000 ints = 6,440,000 B (16B aligned)

// per-gaussian record: 5 float4s (80 B)
// q0 = (A00, A01, A02, A11)
// q1 = (A12, A22, opac, mx)
// q2 = (my, mz, loPack[int], hiPack[int])
// q3 = feats[0..3], q4 = feats[4..7]

__global__ __launch_bounds__(256) void prep_fill_kernel(
    const float* __restrict__ means, const float* __restrict__ opac,
    const float* __restrict__ cov, const float* __restrict__ feat,
    int* __restrict__ ws, float4* __restrict__ recs, int G)
{
    const int g = blockIdx.x*256 + threadIdx.x;
    if (g >= G) return;

    const float lox = -40.f, loy = -40.f, loz = -1.f;
    const float hix =  40.f, hiy =  40.f, hiz =  5.4f;
    const float mx = means[g*3+0], my = means[g*3+1], mz = means[g*3+2];
    const float c00 = cov[g*9+0], c01 = cov[g*9+1], c02 = cov[g*9+2];
    const float c10 = cov[g*9+3], c11 = cov[g*9+4], c12 = cov[g*9+5];
    const float c20 = cov[g*9+6], c21 = cov[g*9+7], c22 = cov[g*9+8];

    const float sx = sqrtf(c00), sy = sqrtf(c11), sz = sqrtf(c22);
    const float blx = mx - 3.0f*sx, bly = my - 3.0f*sy, blz = mz - 3.0f*sz;
    const float bhx = mx + 3.0f*sx, bhy = my + 3.0f*sy, bhz = mz + 3.0f*sz;
    const bool valid = (bhx > lox) & (bhy > loy) & (bhz > loz)
                     & (blx < hix) & (bly < hiy) & (blz < hiz);
    if (!valid) return;

    float blxc = fminf(fmaxf(blx, lox), hix);
    float blyc = fminf(fmaxf(bly, loy), hiy);
    float blzc = fminf(fmaxf(blz, loz), hiz);
    float bhxc = fminf(fmaxf(bhx, lox), hix);
    float bhyc = fminf(fmaxf(bhy, loy), hiy);
    float bhzc = fminf(fmaxf(bhz, loz), hiz);
    int ilox = (int)((blxc - lox) / 0.4f);
    int iloy = (int)((blyc - loy) / 0.4f);
    int iloz = (int)((blzc - loz) / 0.4f);
    int ihix = (int)((bhxc - lox) / 0.4f);
    int ihiy = (int)((bhyc - loy) / 0.4f);
    int ihiz = (int)((bhzc - loz) / 0.4f);
    ilox = min(ilox, GX-1); iloy = min(iloy, GY-1); iloz = min(iloz, GZ-1);
    ihix = min(ihix, GX-1); ihiy = min(ihiy, GY-1); ihiz = min(ihiz, GZ-1);

    // inverse covariance (adjugate / det) — identical formula to prior rounds
    const float m00 = c11*c22 - c12*c21;
    const float m01 = c10*c22 - c12*c20;
    const float m02 = c10*c21 - c11*c20;
    const float det = c00*m00 - c01*m01 + c02*m02;
    const float idet = 1.0f / det;

    float4 q0, q1, q2, q3, q4;
    q0.x = m00 * idet;
    q0.y = (c02*c21 - c01*c22) * idet;
    q0.z = (c01*c12 - c02*c11) * idet;
    q0.w = (c00*c22 - c02*c20) * idet;
    q1.x = (c02*c10 - c00*c12) * idet;
    q1.y = (c00*c11 - c01*c10) * idet;
    q1.z = opac[g];
    q1.w = mx;
    q2.x = my;
    q2.y = mz;
    q2.z = __int_as_float(ilox | (iloy<<8) | (iloz<<16));
    q2.w = __int_as_float(ihix | (ihiy<<8) | (ihiz<<16));
    q3.x = feat[g*8+0]; q3.y = feat[g*8+1]; q3.z = feat[g*8+2]; q3.w = feat[g*8+3];
    q4.x = feat[g*8+4]; q4.y = feat[g*8+5]; q4.z = feat[g*8+6]; q4.w = feat[g*8+7];

    float4* r = recs + (size_t)g * 5;
    r[0] = q0; r[1] = q1; r[2] = q2; r[3] = q3; r[4] = q4;

    // bin into (xy-tile, z-slab) buckets
    const int txlo = ilox >> 2, txhi = ihix >> 2;
    const int tylo = iloy >> 2, tyhi = ihiy >> 2;
    const int slo  = iloz >> 2, shi  = ihiz >> 2;
    for (int tx = txlo; tx <= txhi; ++tx)
        for (int ty = tylo; ty <= tyhi; ++ty)
            for (int s = slo; s <= shi; ++s) {
                const int bin = (tx*NTY + ty)*NSLAB + s;
                const int pos = atomicAdd(&ws[WS_COUNTS + bin], 1);
                if (pos < CAP) ws[WS_BUCKETS + bin*CAP + pos] = g;
            }
}

__global__ __launch_bounds__(256) void gather_kernel(
    const int* __restrict__ ws, const float4* __restrict__ recs,
    float* __restrict__ dens_out, float* __restrict__ feat_out)
{
    const int tile = blockIdx.x;
    const int tx = tile / NTY, ty = tile % NTY;
    const int t = threadIdx.x;
    const int w = t >> 6, l = t & 63;          // wave w owns z-slab [4w, 4w+4)
    const int lx = l >> 4, ly = (l >> 2) & 3, lz = l & 3;
    const int ix = tx*4 + lx, iy = ty*4 + ly, iz = w*4 + lz;

    const float cx = ((float)ix + 0.5f) * 0.4f + (-40.f);
    const float cy = ((float)iy + 0.5f) * 0.4f + (-40.f);
    const float cz = ((float)iz + 0.5f) * 0.4f + (-1.f);

    const int bin = tile*NSLAB + w;
    const int n = min(ws[WS_COUNTS + bin], CAP);
    const int* __restrict__ bkt = ws + WS_BUCKETS + (size_t)bin*CAP;

    float den = 0.f;
    float f0=0,f1=0,f2=0,f3=0,f4=0,f5=0,f6=0,f7=0;

    for (int j = 0; j < n; ++j) {
        const int g = __builtin_amdgcn_readfirstlane(bkt[j]);
        const float4* __restrict__ r = recs + (size_t)g * 5;
        const float4 q0 = r[0], q1 = r[1], q2 = r[2], q3 = r[3], q4 = r[4];
        const int lo = __float_as_int(q2.z);
        const int hi = __float_as_int(q2.w);
        const int ilox = lo & 0xff, iloy = (lo>>8)&0xff, iloz = (lo>>16)&0xff;
        const int ihix = hi & 0xff, ihiy = (hi>>8)&0xff, ihiz = (hi>>16)&0xff;
        const bool in = (ix >= ilox) & (ix <= ihix) & (iy >= iloy) & (iy <= ihiy)
                      & (iz >= iloz) & (iz <= ihiz);
        const float X = cx - q1.w, Y = cy - q2.x, Z = cz - q2.y;
        const float maha = q0.x*X*X + q0.w*Y*Y + q1.y*Z*Z
                         + 2.0f*(q0.y*X*Y + q0.z*X*Z + q1.x*Y*Z);
        float wgt = q1.z * __expf(-0.5f * maha);
        wgt = in ? wgt : 0.f;                  // straight-line predication
        den += wgt;
        f0 += wgt*q3.x; f1 += wgt*q3.y; f2 += wgt*q3.z; f3 += wgt*q3.w;
        f4 += wgt*q4.x; f5 += wgt*q4.y; f6 += wgt*q4.z; f7 += wgt*q4.w;
    }

    const int flat = (ix*GY + iy)*GZ + iz;
    dens_out[flat] = den;
    const float dc = fmaxf(den, 1e-6f);
    float4 fa, fb;
    fa.x = f0/dc; fa.y = f1/dc; fa.z = f2/dc; fa.w = f3/dc;
    fb.x = f4/dc; fb.y = f5/dc; fb.z = f6/dc; fb.w = f7/dc;
    float4* fp = (float4*)(feat_out + (size_t)flat * NFEAT);
    fp[0] = fa; fp[1] = fb;
}

extern "C" void kernel_launch(void* const* d_in, const int* in_sizes, int n_in,
                              void* d_out, int out_size, void* d_ws, size_t ws_size,
                              hipStream_t stream) {
    const float* means = (const float*)d_in[0];
    const float* opac  = (const float*)d_in[1];
    const float* cov   = (const float*)d_in[2];
    const float* feat  = (const float*)d_in[3];
    const int G = in_sizes[0] / 3;

    float* dens_out = (float*)d_out;
    float* feat_out = dens_out + NVOX;
    int* ws = (int*)d_ws;
    float4* recs = (float4*)((char*)d_ws + (size_t)WS_RECORDS * sizeof(int));

    hipMemsetAsync(ws, 0, NBIN * sizeof(int), stream);
    prep_fill_kernel<<<(G + 255)/256, 256, 0, stream>>>(means, opac, cov, feat,
                                                        ws, recs, G);
    gather_kernel<<<NTILES, 256, 0, stream>>>(ws, recs, dens_out, feat_out);
}

// Round 5
// 102.210 us; speedup vs baseline: 8.2994x; 1.1061x over previous
//
#include <hip/hip_runtime.h>

#define GX 200
#define GY 200
#define GZ 16
#define NVOX (GX*GY*GZ)
#define NFEAT 8

#define NTX 50
#define NTY 50
#define NTILES (NTX*NTY)      // 2500 xy-tiles of 4x4 voxels
#define NSLAB 4               // z split into 4 slabs of 4 voxels
#define NBIN (NTILES*NSLAB)   // 10000 bins
#define CAP 160               // per-bin capacity (avg ~30, max span 3x3x3 bins)

// ws layout (ints): [0,NBIN) counts | [NBIN, NBIN+NBIN*CAP) buckets | records
#define WS_COUNTS 0
#define WS_BUCKETS NBIN
#define WS_RECORDS (NBIN + NBIN*CAP)   // int offset; 16B-aligned (1,610,000*4 B)

// per-gaussian record: 5 float4s (80 B)
// q0=(A00,A01,A02,A11) q1=(A12,A22,opac,mx) q2=(my,mz,loPack,hiPack) q3=f[0..3] q4=f[4..7]

// 16 threads per gaussian: slot s in [0,16) = (sx=s>>2, sy=s&3) xy-tile offset.
// Each active slot does <=3 slab atomics (serial chain ~9x shorter than r4),
// 2048 blocks -> 8 waves/SIMD of latency hiding for the atomic chains.
__global__ __launch_bounds__(256) void prep_fill_kernel(
    const float* __restrict__ means, const float* __restrict__ opac,
    const float* __restrict__ cov, const float* __restrict__ feat,
    int* __restrict__ ws, float4* __restrict__ recs, int G)
{
    const int i = blockIdx.x*256 + threadIdx.x;
    const int g = i >> 4, s = i & 15;
    if (g >= G) return;

    const float lox = -40.f, loy = -40.f, loz = -1.f;
    const float hix =  40.f, hiy =  40.f, hiz =  5.4f;
    const float mx = means[g*3+0], my = means[g*3+1], mz = means[g*3+2];
    const float c00 = cov[g*9+0], c01 = cov[g*9+1], c02 = cov[g*9+2];
    const float c10 = cov[g*9+3], c11 = cov[g*9+4], c12 = cov[g*9+5];
    const float c20 = cov[g*9+6], c21 = cov[g*9+7], c22 = cov[g*9+8];

    const float sx = sqrtf(c00), sy = sqrtf(c11), sz = sqrtf(c22);
    const float blx = mx - 3.0f*sx, bly = my - 3.0f*sy, blz = mz - 3.0f*sz;
    const float bhx = mx + 3.0f*sx, bhy = my + 3.0f*sy, bhz = mz + 3.0f*sz;
    const bool valid = (bhx > lox) & (bhy > loy) & (bhz > loz)
                     & (blx < hix) & (bly < hiy) & (blz < hiz);
    if (!valid) return;

    float blxc = fminf(fmaxf(blx, lox), hix);
    float blyc = fminf(fmaxf(bly, loy), hiy);
    float blzc = fminf(fmaxf(blz, loz), hiz);
    float bhxc = fminf(fmaxf(bhx, lox), hix);
    float bhyc = fminf(fmaxf(bhy, loy), hiy);
    float bhzc = fminf(fmaxf(bhz, loz), hiz);
    int ilox = (int)((blxc - lox) / 0.4f);
    int iloy = (int)((blyc - loy) / 0.4f);
    int iloz = (int)((blzc - loz) / 0.4f);
    int ihix = (int)((bhxc - lox) / 0.4f);
    int ihiy = (int)((bhyc - loy) / 0.4f);
    int ihiz = (int)((bhzc - loz) / 0.4f);
    ilox = min(ilox, GX-1); iloy = min(iloy, GY-1); iloz = min(iloz, GZ-1);
    ihix = min(ihix, GX-1); ihiy = min(ihiy, GY-1); ihiz = min(ihiz, GZ-1);

    // record write: lanes s=0..4 each store one float4 (contiguous 80 B)
    if (s < 5) {
        const float m00 = c11*c22 - c12*c21;
        const float m01 = c10*c22 - c12*c20;
        const float m02 = c10*c21 - c11*c20;
        const float det = c00*m00 - c01*m01 + c02*m02;
        const float idet = 1.0f / det;
        float4 q;
        if (s == 0) {
            q.x = m00 * idet;
            q.y = (c02*c21 - c01*c22) * idet;
            q.z = (c01*c12 - c02*c11) * idet;
            q.w = (c00*c22 - c02*c20) * idet;
        } else if (s == 1) {
            q.x = (c02*c10 - c00*c12) * idet;
            q.y = (c00*c11 - c01*c10) * idet;
            q.z = opac[g];
            q.w = mx;
        } else if (s == 2) {
            q.x = my;
            q.y = mz;
            q.z = __int_as_float(ilox | (iloy<<8) | (iloz<<16));
            q.w = __int_as_float(ihix | (ihiy<<8) | (ihiz<<16));
        } else if (s == 3) {
            q.x = feat[g*8+0]; q.y = feat[g*8+1]; q.z = feat[g*8+2]; q.w = feat[g*8+3];
        } else {
            q.x = feat[g*8+4]; q.y = feat[g*8+5]; q.z = feat[g*8+6]; q.w = feat[g*8+7];
        }
        recs[(size_t)g*5 + s] = q;
    }

    // binning: slot (s>>2, s&3) covers xy-tile (txlo+sx, tylo+sy)
    const int txlo = ilox >> 2, txhi = ihix >> 2;
    const int tylo = iloy >> 2, tyhi = ihiy >> 2;
    const int tx = txlo + (s >> 2);
    const int ty = tylo + (s & 3);
    if (tx <= txhi && ty <= tyhi) {
        const int slo = iloz >> 2, shi = ihiz >> 2;
        const int base = (tx*NTY + ty)*NSLAB;
        for (int sl = slo; sl <= shi; ++sl) {
            const int pos = atomicAdd(&ws[WS_COUNTS + base + sl], 1);
            if (pos < CAP) ws[WS_BUCKETS + (size_t)(base + sl)*CAP + pos] = g;
        }
    }
}

__global__ __launch_bounds__(256) void gather_kernel(
    const int* __restrict__ ws, const float4* __restrict__ recs,
    float* __restrict__ dens_out, float* __restrict__ feat_out)
{
    const int tile = blockIdx.x;
    const int tx = tile / NTY, ty = tile % NTY;
    const int t = threadIdx.x;
    const int w = t >> 6, l = t & 63;          // wave w owns z-slab [4w, 4w+4)
    const int lx = l >> 4, ly = (l >> 2) & 3, lz = l & 3;
    const int ix = tx*4 + lx, iy = ty*4 + ly, iz = w*4 + lz;

    const float cx = ((float)ix + 0.5f) * 0.4f + (-40.f);
    const float cy = ((float)iy + 0.5f) * 0.4f + (-40.f);
    const float cz = ((float)iz + 0.5f) * 0.4f + (-1.f);

    const int bin = tile*NSLAB + w;
    const int n = min(ws[WS_COUNTS + bin], CAP);
    const int* __restrict__ bkt = ws + WS_BUCKETS + (size_t)bin*CAP;

    float den = 0.f;
    float f0=0,f1=0,f2=0,f3=0,f4=0,f5=0,f6=0,f7=0;

    int gnext = (n > 0) ? bkt[0] : 0;
    for (int j = 0; j < n; ++j) {
        const int g = __builtin_amdgcn_readfirstlane(gnext);
        gnext = (j + 1 < n) ? bkt[j + 1] : 0;   // prefetch next id
        const float4* __restrict__ r = recs + (size_t)g * 5;
        const float4 q0 = r[0], q1 = r[1], q2 = r[2], q3 = r[3], q4 = r[4];
        const int lo = __float_as_int(q2.z);
        const int hi = __float_as_int(q2.w);
        const int ilox = lo & 0xff, iloy = (lo>>8)&0xff, iloz = (lo>>16)&0xff;
        const int ihix = hi & 0xff, ihiy = (hi>>8)&0xff, ihiz = (hi>>16)&0xff;
        const bool in = (ix >= ilox) & (ix <= ihix) & (iy >= iloy) & (iy <= ihiy)
                      & (iz >= iloz) & (iz <= ihiz);
        const float X = cx - q1.w, Y = cy - q2.x, Z = cz - q2.y;
        const float maha = q0.x*X*X + q0.w*Y*Y + q1.y*Z*Z
                         + 2.0f*(q0.y*X*Y + q0.z*X*Z + q1.x*Y*Z);
        float wgt = q1.z * __expf(-0.5f * maha);
        wgt = in ? wgt : 0.f;
        den += wgt;
        f0 += wgt*q3.x; f1 += wgt*q3.y; f2 += wgt*q3.z; f3 += wgt*q3.w;
        f4 += wgt*q4.x; f5 += wgt*q4.y; f6 += wgt*q4.z; f7 += wgt*q4.w;
    }

    const int flat = (ix*GY + iy)*GZ + iz;
    dens_out[flat] = den;
    const float dc = fmaxf(den, 1e-6f);
    float4 fa, fb;
    fa.x = f0/dc; fa.y = f1/dc; fa.z = f2/dc; fa.w = f3/dc;
    fb.x = f4/dc; fb.y = f5/dc; fb.z = f6/dc; fb.w = f7/dc;
    float4* fp = (float4*)(feat_out + (size_t)flat * NFEAT);
    fp[0] = fa; fp[1] = fb;
}

extern "C" void kernel_launch(void* const* d_in, const int* in_sizes, int n_in,
                              void* d_out, int out_size, void* d_ws, size_t ws_size,
                              hipStream_t stream) {
    const float* means = (const float*)d_in[0];
    const float* opac  = (const float*)d_in[1];
    const float* cov   = (const float*)d_in[2];
    const float* feat  = (const float*)d_in[3];
    const int G = in_sizes[0] / 3;

    float* dens_out = (float*)d_out;
    float* feat_out = dens_out + NVOX;
    int* ws = (int*)d_ws;
    float4* recs = (float4*)((char*)d_ws + (size_t)WS_RECORDS * sizeof(int));

    hipMemsetAsync(ws, 0, NBIN * sizeof(int), stream);
    prep_fill_kernel<<<(G*16 + 255)/256, 256, 0, stream>>>(means, opac, cov, feat,
                                                           ws, recs, G);
    gather_kernel<<<NTILES, 256, 0, stream>>>(ws, recs, dens_out, feat_out);
}

// Round 6
// 101.216 us; speedup vs baseline: 8.3809x; 1.0098x over previous
//
#include <hip/hip_runtime.h>

#define GX 200
#define GY 200
#define GZ 16
#define NVOX (GX*GY*GZ)
#define NFEAT 8

#define NTX 50
#define NTY 50
#define NTILES (NTX*NTY)      // 2500 xy-tiles of 4x4 voxels
#define NSLAB 4               // z split into 4 slabs of 4 voxels
#define NBIN (NTILES*NSLAB)   // 10000 bins
#define CAP 160               // per-bin capacity (avg ~25)

// ws layout (ints):
//   [0, NBIN)                     counts
//   [NBIN, NBIN + NBIN*CAP*2)     buckets (int2: {gauss id, packed lane-mask})
//   records: 5 float4 per gaussian
#define WS_COUNTS 0
#define WS_BUCKETS NBIN
#define WS_RECORDS (NBIN + NBIN*CAP*2)   // 3,210,000 ints -> 16B aligned

// record: q0=(A00,A01,A02,A11) q1=(A12,A22,opac,mx)
//         q2=(my,mz,f0,f1)     q3=(f2,f3,f4,f5)    q4=(f6,f7,0,0)

__global__ __launch_bounds__(256) void prep_fill_kernel(
    const float* __restrict__ means, const float* __restrict__ opac,
    const float* __restrict__ cov, const float* __restrict__ feat,
    int* __restrict__ ws, float4* __restrict__ recs, int G)
{
    const int i = blockIdx.x*256 + threadIdx.x;
    const int g = i >> 4, s = i & 15;
    if (g >= G) return;

    const float lox = -40.f, loy = -40.f, loz = -1.f;
    const float hix =  40.f, hiy =  40.f, hiz =  5.4f;
    const float mx = means[g*3+0], my = means[g*3+1], mz = means[g*3+2];
    const float c00 = cov[g*9+0], c01 = cov[g*9+1], c02 = cov[g*9+2];
    const float c10 = cov[g*9+3], c11 = cov[g*9+4], c12 = cov[g*9+5];
    const float c20 = cov[g*9+6], c21 = cov[g*9+7], c22 = cov[g*9+8];

    const float sx = sqrtf(c00), sy = sqrtf(c11), sz = sqrtf(c22);
    const float blx = mx - 3.0f*sx, bly = my - 3.0f*sy, blz = mz - 3.0f*sz;
    const float bhx = mx + 3.0f*sx, bhy = my + 3.0f*sy, bhz = mz + 3.0f*sz;
    const bool valid = (bhx > lox) & (bhy > loy) & (bhz > loz)
                     & (blx < hix) & (bly < hiy) & (blz < hiz);
    if (!valid) return;

    float blxc = fminf(fmaxf(blx, lox), hix);
    float blyc = fminf(fmaxf(bly, loy), hiy);
    float blzc = fminf(fmaxf(blz, loz), hiz);
    float bhxc = fminf(fmaxf(bhx, lox), hix);
    float bhyc = fminf(fmaxf(bhy, loy), hiy);
    float bhzc = fminf(fmaxf(bhz, loz), hiz);
    int ilox = (int)((blxc - lox) / 0.4f);
    int iloy = (int)((blyc - loy) / 0.4f);
    int iloz = (int)((blzc - loz) / 0.4f);
    int ihix = (int)((bhxc - lox) / 0.4f);
    int ihiy = (int)((bhyc - loy) / 0.4f);
    int ihiz = (int)((bhzc - loz) / 0.4f);
    ilox = min(ilox, GX-1); iloy = min(iloy, GY-1); iloz = min(iloz, GZ-1);
    ihix = min(ihix, GX-1); ihiy = min(ihiy, GY-1); ihiz = min(ihiz, GZ-1);

    // record write: lanes s=0..4 each store one float4 (contiguous 80 B)
    if (s < 5) {
        const float m00 = c11*c22 - c12*c21;
        const float m01 = c10*c22 - c12*c20;
        const float m02 = c10*c21 - c11*c20;
        const float det = c00*m00 - c01*m01 + c02*m02;
        const float idet = 1.0f / det;
        float4 q;
        if (s == 0) {
            q.x = m00 * idet;
            q.y = (c02*c21 - c01*c22) * idet;
            q.z = (c01*c12 - c02*c11) * idet;
            q.w = (c00*c22 - c02*c20) * idet;
        } else if (s == 1) {
            q.x = (c02*c10 - c00*c12) * idet;
            q.y = (c00*c11 - c01*c10) * idet;
            q.z = opac[g];
            q.w = mx;
        } else if (s == 2) {
            q.x = my;
            q.y = mz;
            q.z = feat[g*8+0];
            q.w = feat[g*8+1];
        } else if (s == 3) {
            q.x = feat[g*8+2]; q.y = feat[g*8+3]; q.z = feat[g*8+4]; q.w = feat[g*8+5];
        } else {
            q.x = feat[g*8+6]; q.y = feat[g*8+7]; q.z = 0.f; q.w = 0.f;
        }
        recs[(size_t)g*5 + s] = q;
    }

    // binning: slot (s>>2, s&3) covers xy-tile (txlo + s>>2, tylo + s&3)
    const int txlo = ilox >> 2, txhi = ihix >> 2;
    const int tylo = iloy >> 2, tyhi = ihiy >> 2;
    const int tx = txlo + (s >> 2);
    const int ty = tylo + (s & 3);
    if (tx <= txhi && ty <= tyhi) {
        // per-(gaussian,tile) xy lane mask: bit (lx*4+ly) set iff voxel in box
        const int lxlo = max(ilox - tx*4, 0), lxhi = min(ihix - tx*4, 3);
        const int lylo = max(iloy - ty*4, 0), lyhi = min(ihiy - ty*4, 3);
        const int xm = ((1 << (lxhi+1)) - 1) & ~((1 << lxlo) - 1);   // 4 bits
        const int ym = ((1 << (lyhi+1)) - 1) & ~((1 << lylo) - 1);   // 4 bits
        const int spread = (xm & 1) + (xm & 2)*8 + (xm & 4)*64 + (xm & 8)*512;
        const int xymask = ym * spread;                               // 16 bits

        const int slo = iloz >> 2, shi = ihiz >> 2;
        const int base = (tx*NTY + ty)*NSLAB;
        int2* __restrict__ bkt = (int2*)(ws + WS_BUCKETS);
        for (int sl = slo; sl <= shi; ++sl) {
            const int lzlo = max(iloz - sl*4, 0), lzhi = min(ihiz - sl*4, 3);
            const int zm = ((1 << (lzhi+1)) - 1) & ~((1 << lzlo) - 1);
            const int pos = atomicAdd(&ws[WS_COUNTS + base + sl], 1);
            if (pos < CAP) {
                int2 e; e.x = g; e.y = xymask | (zm << 16);
                bkt[(size_t)(base + sl)*CAP + pos] = e;
            }
        }
    }
}

__global__ __launch_bounds__(256) void gather_kernel(
    const int* __restrict__ ws, const float4* __restrict__ recs,
    float* __restrict__ dens_out, float* __restrict__ feat_out)
{
    const int tile = blockIdx.x;
    const int tx = tile / NTY, ty = tile % NTY;
    const int t = threadIdx.x;
    const int w = t >> 6, l = t & 63;          // wave w owns z-slab [4w, 4w+4)
    const int lx = l >> 4, ly = (l >> 2) & 3, lz = l & 3;
    const int ix = tx*4 + lx, iy = ty*4 + ly, iz = w*4 + lz;
    const int sh_xy = lx*4 + ly;               // bit index in xymask
    const int sh_z  = 16 + lz;                 // bit index of zmask

    const float cx = ((float)ix + 0.5f) * 0.4f + (-40.f);
    const float cy = ((float)iy + 0.5f) * 0.4f + (-40.f);
    const float cz = ((float)iz + 0.5f) * 0.4f + (-1.f);

    const int bin = tile*NSLAB + w;
    const int n = min(ws[WS_COUNTS + bin], CAP);
    const int2* __restrict__ bkt = (const int2*)(ws + WS_BUCKETS) + (size_t)bin*CAP;

    float den = 0.f;
    float2 a01 = {0.f,0.f}, a23 = {0.f,0.f}, a45 = {0.f,0.f}, a67 = {0.f,0.f};

    int2 e = (n > 0) ? bkt[0] : int2{0,0};
    for (int j = 0; j < n; ++j) {
        const int g = __builtin_amdgcn_readfirstlane(e.x);
        const int msk = e.y;
        if (j + 1 < n) e = bkt[j + 1];          // prefetch next entry
        const float4* __restrict__ r = recs + (size_t)g * 5;
        const float4 q0 = r[0], q1 = r[1], q2 = r[2], q3 = r[3];
        const float2 q4 = *(const float2*)(r + 4);

        // 2-shift box test from precomputed lane masks
        const bool in = ((msk >> sh_xy) & (msk >> sh_z) & 1) != 0;

        const float X = cx - q1.w, Y = cy - q2.x, Z = cz - q2.y;
        const float maha = q0.x*X*X + q0.w*Y*Y + q1.y*Z*Z
                         + 2.0f*(q0.y*X*Y + q0.z*X*Z + q1.x*Y*Z);
        float wgt = q1.z * __expf(-0.5f * maha);
        wgt = in ? wgt : 0.f;
        den += wgt;
        const float2 w2 = {wgt, wgt};
        a01.x += w2.x*q2.z; a01.y += w2.y*q2.w;   // f0,f1
        a23.x += w2.x*q3.x; a23.y += w2.y*q3.y;   // f2,f3
        a45.x += w2.x*q3.z; a45.y += w2.y*q3.w;   // f4,f5
        a67.x += w2.x*q4.x; a67.y += w2.y*q4.y;   // f6,f7
    }

    const int flat = (ix*GY + iy)*GZ + iz;
    dens_out[flat] = den;
    const float dc = fmaxf(den, 1e-6f);
    float4 fa, fb;
    fa.x = a01.x/dc; fa.y = a01.y/dc; fa.z = a23.x/dc; fa.w = a23.y/dc;
    fb.x = a45.x/dc; fb.y = a45.y/dc; fb.z = a67.x/dc; fb.w = a67.y/dc;
    float4* fp = (float4*)(feat_out + (size_t)flat * NFEAT);
    fp[0] = fa; fp[1] = fb;
}

extern "C" void kernel_launch(void* const* d_in, const int* in_sizes, int n_in,
                              void* d_out, int out_size, void* d_ws, size_t ws_size,
                              hipStream_t stream) {
    const float* means = (const float*)d_in[0];
    const float* opac  = (const float*)d_in[1];
    const float* cov   = (const float*)d_in[2];
    const float* feat  = (const float*)d_in[3];
    const int G = in_sizes[0] / 3;

    float* dens_out = (float*)d_out;
    float* feat_out = dens_out + NVOX;
    int* ws = (int*)d_ws;
    float4* recs = (float4*)((char*)d_ws + (size_t)WS_RECORDS * sizeof(int));

    hipMemsetAsync(ws, 0, NBIN * sizeof(int), stream);
    prep_fill_kernel<<<(G*16 + 255)/256, 256, 0, stream>>>(means, opac, cov, feat,
                                                           ws, recs, G);
    gather_kernel<<<NTILES, 256, 0, stream>>>(ws, recs, dens_out, feat_out);
}